// Round 1
// baseline (957.411 us; speedup 1.0000x reference)
//
#include <hip/hip_runtime.h>

#define POOL_SHIFT 2
#define GRID_DIM 64
#define NUM_CELLS 4096
#define NCH 64
#define OUT_ELEMS (64 * 4096 * 64)   // B * NUM_CELLS * C = 16,777,216

// Monotonic order-preserving float->uint encoding.
// Any finite/normal float encodes to > 0, so 0 works as "empty" sentinel.
__device__ __forceinline__ unsigned int encode_f32(float f) {
    unsigned int b = __float_as_uint(f);
    return (b & 0x80000000u) ? ~b : (b | 0x80000000u);
}

__device__ __forceinline__ float decode_f32(unsigned int u) {
    unsigned int b = (u & 0x80000000u) ? (u & 0x7FFFFFFFu) : ~u;
    return __uint_as_float(b);
}

// ---------------- kernel 1: zero-init output (as u32) ----------------
__global__ __launch_bounds__(256) void init_kernel(uint4* __restrict__ out) {
    const int n4 = OUT_ELEMS / 4;  // 4,194,304
    int i = blockIdx.x * blockDim.x + threadIdx.x;
    int stride = gridDim.x * blockDim.x;
    uint4 z = make_uint4(0u, 0u, 0u, 0u);
    for (; i < n4; i += stride) out[i] = z;
}

// ---------------- kernel 2: scatter atomicMax ----------------
// 16 threads per point; thread t handles channels [4*(t%16) .. 4*(t%16)+3]
__global__ __launch_bounds__(256) void scatter_kernel(
    const float* __restrict__ x, const int* __restrict__ pos,
    const int* __restrict__ batch, unsigned int* __restrict__ out, int n) {
    int t = blockIdx.x * blockDim.x + threadIdx.x;
    int p = t >> 4;
    int chunk = t & 15;
    if (p >= n) return;

    int b  = batch[p];
    int px = pos[2 * p];
    int py = pos[2 * p + 1];
    int idx = b * NUM_CELLS + (px >> POOL_SHIFT) * GRID_DIM + (py >> POOL_SHIFT);

    const float4 v = ((const float4*)(x + (size_t)p * NCH))[chunk];
    unsigned int* o = out + (size_t)idx * NCH + chunk * 4;

    atomicMax(o + 0, encode_f32(v.x));
    atomicMax(o + 1, encode_f32(v.y));
    atomicMax(o + 2, encode_f32(v.z));
    atomicMax(o + 3, encode_f32(v.w));
}

// ---------------- kernel 3: decode in place ----------------
__global__ __launch_bounds__(256) void decode_kernel(unsigned int* __restrict__ out) {
    const int n4 = OUT_ELEMS / 4;
    int i = blockIdx.x * blockDim.x + threadIdx.x;
    int stride = gridDim.x * blockDim.x;
    for (; i < n4; i += stride) {
        uint4 u = ((const uint4*)out)[i];
        float4 f;
        f.x = (u.x == 0u) ? 0.0f : decode_f32(u.x);
        f.y = (u.y == 0u) ? 0.0f : decode_f32(u.y);
        f.z = (u.z == 0u) ? 0.0f : decode_f32(u.z);
        f.w = (u.w == 0u) ? 0.0f : decode_f32(u.w);
        ((float4*)out)[i] = f;
    }
}

extern "C" void kernel_launch(void* const* d_in, const int* in_sizes, int n_in,
                              void* d_out, int out_size, void* d_ws, size_t ws_size,
                              hipStream_t stream) {
    const float* x   = (const float*)d_in[0];
    const int* pos   = (const int*)d_in[1];
    const int* batch = (const int*)d_in[2];
    unsigned int* out_u = (unsigned int*)d_out;

    int n = in_sizes[2];  // N points (batch has N elements)

    // 1) zero-init output
    {
        int n4 = OUT_ELEMS / 4;
        int blocks = (n4 + 255) / 256;
        if (blocks > 4096) blocks = 4096;  // grid-stride
        init_kernel<<<blocks, 256, 0, stream>>>((uint4*)d_out);
    }
    // 2) scatter
    {
        long long threads = (long long)n * 16;
        int blocks = (int)((threads + 255) / 256);
        scatter_kernel<<<blocks, 256, 0, stream>>>(x, pos, batch, out_u, n);
    }
    // 3) decode
    {
        int n4 = OUT_ELEMS / 4;
        int blocks = (n4 + 255) / 256;
        if (blocks > 4096) blocks = 4096;
        decode_kernel<<<blocks, 256, 0, stream>>>(out_u);
    }
}

// Round 2
// 456.428 us; speedup vs baseline: 2.0976x; 2.0976x over previous
//
#include <hip/hip_runtime.h>

#define POOL_SHIFT 2
#define GRID_DIM 64
#define NUM_CELLS 4096
#define NCH 64
#define BATCH 64
#define NSEG (BATCH * NUM_CELLS)   // 262,144 cells
#define NIL 0xFFFFFFFFu

// ---------------- kernel 1: build per-cell linked lists ----------------
// head[cell] -> most recent point; next[p] -> previous head.
// Race-free: next[p] is only read by the NEXT kernel (launch boundary syncs).
__global__ __launch_bounds__(256) void build_lists(
    const int* __restrict__ pos, const int* __restrict__ batch,
    unsigned int* __restrict__ head, unsigned int* __restrict__ next, int n) {
    int p = blockIdx.x * blockDim.x + threadIdx.x;
    if (p >= n) return;
    int b  = batch[p];
    int px = pos[2 * p];
    int py = pos[2 * p + 1];
    int idx = b * NUM_CELLS + (px >> POOL_SHIFT) * GRID_DIM + (py >> POOL_SHIFT);
    unsigned int old = atomicExch(&head[idx], (unsigned int)p);
    next[p] = old;
}

// ---------------- kernel 2: one wave per cell, lane = channel ----------------
__global__ __launch_bounds__(256) void gather_max(
    const float* __restrict__ x, const unsigned int* __restrict__ head,
    const unsigned int* __restrict__ next, float* __restrict__ out) {
    int wave = (int)((blockIdx.x * blockDim.x + threadIdx.x) >> 6);
    int lane = threadIdx.x & 63;
    if (wave >= NSEG) return;

    unsigned int p = head[wave];           // broadcast load (all lanes same addr)
    size_t obase = (size_t)wave * NCH + lane;
    if (p == NIL) {                        // empty cell -> 0 (reference semantics)
        out[obase] = 0.0f;
        return;
    }
    float acc = -__builtin_inff();
    while (p != NIL) {
        unsigned int np = next[p];                 // independent of row load
        float v = x[(size_t)p * NCH + lane];       // 64 lanes x 4B = coalesced row
        acc = fmaxf(acc, v);
        p = np;
    }
    out[obase] = acc;
}

extern "C" void kernel_launch(void* const* d_in, const int* in_sizes, int n_in,
                              void* d_out, int out_size, void* d_ws, size_t ws_size,
                              hipStream_t stream) {
    const float* x   = (const float*)d_in[0];
    const int* pos   = (const int*)d_in[1];
    const int* batch = (const int*)d_in[2];
    float* out = (float*)d_out;

    int n = in_sizes[2];  // N points

    unsigned int* head = (unsigned int*)d_ws;          // NSEG u32 (1 MB)
    unsigned int* next = head + NSEG;                  // N u32 (4 MB)

    // head = NIL (ws is re-poisoned to 0xAA before every launch)
    hipMemsetAsync(head, 0xFF, (size_t)NSEG * sizeof(unsigned int), stream);

    {
        int blocks = (n + 255) / 256;
        build_lists<<<blocks, 256, 0, stream>>>(pos, batch, head, next, n);
    }
    {
        // one 64-lane wave per cell, 4 waves per block
        int blocks = NSEG / 4;  // 65,536
        gather_max<<<blocks, 256, 0, stream>>>(x, head, next, out);
    }
}

// Round 3
// 446.926 us; speedup vs baseline: 2.1422x; 1.0213x over previous
//
#include <hip/hip_runtime.h>

#define POOL_SHIFT 2
#define GRID_DIM 64
#define NUM_CELLS 4096
#define NCH 64
#define BATCH 64
#define NSEG (BATCH * NUM_CELLS)   // 262,144 cells
#define SCAN_BLOCKS 1024           // NSEG / 256

__device__ __forceinline__ int cell_of(const int* __restrict__ pos,
                                       const int* __restrict__ batch, int p) {
    int b  = batch[p];
    int px = pos[2 * p];
    int py = pos[2 * p + 1];
    return b * NUM_CELLS + (px >> POOL_SHIFT) * GRID_DIM + (py >> POOL_SHIFT);
}

// ---- K1: histogram + per-point rank within its cell ----
__global__ __launch_bounds__(256) void count_kernel(
    const int* __restrict__ pos, const int* __restrict__ batch,
    unsigned int* __restrict__ counts, unsigned int* __restrict__ rank, int n) {
    int p = blockIdx.x * blockDim.x + threadIdx.x;
    if (p >= n) return;
    int c = cell_of(pos, batch, p);
    rank[p] = atomicAdd(&counts[c], 1u);
}

// ---- K2a: per-256-chunk sums ----
__global__ __launch_bounds__(256) void reduce_kernel(
    const unsigned int* __restrict__ counts, unsigned int* __restrict__ blocksum) {
    __shared__ unsigned int s[256];
    int t = threadIdx.x;
    s[t] = counts[blockIdx.x * 256 + t];
    __syncthreads();
    for (int off = 128; off > 0; off >>= 1) {
        if (t < off) s[t] += s[t + off];
        __syncthreads();
    }
    if (t == 0) blocksum[blockIdx.x] = s[0];
}

// ---- K2b: exclusive scan of the 1024 chunk sums (single block) ----
__global__ __launch_bounds__(1024) void scanblock_kernel(
    const unsigned int* __restrict__ blocksum, unsigned int* __restrict__ blockbase) {
    __shared__ unsigned int s[1024];
    int t = threadIdx.x;
    unsigned int own = blocksum[t];
    s[t] = own;
    __syncthreads();
    for (int off = 1; off < 1024; off <<= 1) {
        unsigned int v = (t >= off) ? s[t - off] : 0u;
        __syncthreads();
        s[t] += v;
        __syncthreads();
    }
    blockbase[t] = s[t] - own;   // exclusive
}

// ---- K2c: per-chunk exclusive scan + base -> global offsets ----
__global__ __launch_bounds__(256) void offsets_kernel(
    const unsigned int* __restrict__ counts, const unsigned int* __restrict__ blockbase,
    unsigned int* __restrict__ offsets, int n) {
    __shared__ unsigned int s[256];
    int t = threadIdx.x, b = blockIdx.x;
    unsigned int own = counts[b * 256 + t];
    s[t] = own;
    __syncthreads();
    for (int off = 1; off < 256; off <<= 1) {
        unsigned int v = (t >= off) ? s[t - off] : 0u;
        __syncthreads();
        s[t] += v;
        __syncthreads();
    }
    unsigned int incl = s[t] + blockbase[b];
    offsets[b * 256 + t] = incl - own;               // exclusive
    if (b == SCAN_BLOCKS - 1 && t == 255) offsets[NSEG] = incl;  // == n
}

// ---- K3: scatter point ids into cell-sorted order ----
__global__ __launch_bounds__(256) void reorder_kernel(
    const int* __restrict__ pos, const int* __restrict__ batch,
    const unsigned int* __restrict__ rank, const unsigned int* __restrict__ offsets,
    unsigned int* __restrict__ order, int n) {
    int p = blockIdx.x * blockDim.x + threadIdx.x;
    if (p >= n) return;
    int c = cell_of(pos, batch, p);
    order[offsets[c] + rank[p]] = (unsigned int)p;
}

// ---- K4: one wave per cell, lane = channel; independent row loads ----
__global__ __launch_bounds__(256) void gather_kernel(
    const float* __restrict__ x, const unsigned int* __restrict__ offsets,
    const unsigned int* __restrict__ order, float* __restrict__ out) {
    int wave = (int)((blockIdx.x * blockDim.x + threadIdx.x) >> 6);
    int lane = threadIdx.x & 63;
    unsigned int s = (unsigned int)__builtin_amdgcn_readfirstlane((int)offsets[wave]);
    unsigned int e = (unsigned int)__builtin_amdgcn_readfirstlane((int)offsets[wave + 1]);

    size_t obase = (size_t)wave * NCH + lane;
    if (s == e) { out[obase] = 0.0f; return; }  // empty cell -> 0

    float acc = -__builtin_inff();
    unsigned int i = s;
    for (; i + 4 <= e; i += 4) {
        unsigned int p0 = order[i], p1 = order[i + 1],
                     p2 = order[i + 2], p3 = order[i + 3];
        float v0 = x[(size_t)p0 * NCH + lane];
        float v1 = x[(size_t)p1 * NCH + lane];
        float v2 = x[(size_t)p2 * NCH + lane];
        float v3 = x[(size_t)p3 * NCH + lane];
        acc = fmaxf(acc, fmaxf(fmaxf(v0, v1), fmaxf(v2, v3)));
    }
    for (; i < e; ++i) {
        unsigned int p = order[i];
        acc = fmaxf(acc, x[(size_t)p * NCH + lane]);
    }
    out[obase] = acc;
}

extern "C" void kernel_launch(void* const* d_in, const int* in_sizes, int n_in,
                              void* d_out, int out_size, void* d_ws, size_t ws_size,
                              hipStream_t stream) {
    const float* x   = (const float*)d_in[0];
    const int* pos   = (const int*)d_in[1];
    const int* batch = (const int*)d_in[2];
    float* out = (float*)d_out;
    int n = in_sizes[2];

    // workspace layout (~10 MB)
    unsigned int* counts    = (unsigned int*)d_ws;          // NSEG
    unsigned int* offsets   = counts + NSEG;                // NSEG + 1
    unsigned int* blocksum  = offsets + NSEG + 1;           // 1024
    unsigned int* blockbase = blocksum + 1024;              // 1024
    unsigned int* rank      = blockbase + 1024;             // N
    unsigned int* order     = rank + n;                     // N

    hipMemsetAsync(counts, 0, (size_t)NSEG * sizeof(unsigned int), stream);

    int pblocks = (n + 255) / 256;
    count_kernel<<<pblocks, 256, 0, stream>>>(pos, batch, counts, rank, n);
    reduce_kernel<<<SCAN_BLOCKS, 256, 0, stream>>>(counts, blocksum);
    scanblock_kernel<<<1, 1024, 0, stream>>>(blocksum, blockbase);
    offsets_kernel<<<SCAN_BLOCKS, 256, 0, stream>>>(counts, blockbase, offsets, n);
    reorder_kernel<<<pblocks, 256, 0, stream>>>(pos, batch, rank, offsets, order, n);
    gather_kernel<<<NSEG / 4, 256, 0, stream>>>(x, offsets, order, out);
}

// Round 4
// 446.191 us; speedup vs baseline: 2.1457x; 1.0016x over previous
//
#include <hip/hip_runtime.h>

#define POOL_SHIFT 2
#define GRID_DIM 64
#define NUM_CELLS 4096
#define NCH 64
#define BATCH 64
#define NSEG (BATCH * NUM_CELLS)   // 262,144 cells
#define SCAN_BLOCKS 1024           // NSEG / 256

// ---- K1: histogram + per-point rank + cached cell id ----
__global__ __launch_bounds__(256) void count_kernel(
    const int* __restrict__ pos, const int* __restrict__ batch,
    unsigned int* __restrict__ counts, unsigned int* __restrict__ rank,
    int* __restrict__ cell, int n) {
    int p = blockIdx.x * blockDim.x + threadIdx.x;
    if (p >= n) return;
    int2 pp = ((const int2*)pos)[p];
    int c = batch[p] * NUM_CELLS + (pp.x >> POOL_SHIFT) * GRID_DIM + (pp.y >> POOL_SHIFT);
    cell[p] = c;
    rank[p] = atomicAdd(&counts[c], 1u);
}

// ---- K2a: per-256-chunk sums ----
__global__ __launch_bounds__(256) void reduce_kernel(
    const unsigned int* __restrict__ counts, unsigned int* __restrict__ blocksum) {
    __shared__ unsigned int s[256];
    int t = threadIdx.x;
    s[t] = counts[blockIdx.x * 256 + t];
    __syncthreads();
    for (int off = 128; off > 0; off >>= 1) {
        if (t < off) s[t] += s[t + off];
        __syncthreads();
    }
    if (t == 0) blocksum[blockIdx.x] = s[0];
}

// ---- K2b: exclusive scan of the 1024 chunk sums (single block) ----
__global__ __launch_bounds__(1024) void scanblock_kernel(
    const unsigned int* __restrict__ blocksum, unsigned int* __restrict__ blockbase) {
    __shared__ unsigned int s[1024];
    int t = threadIdx.x;
    unsigned int own = blocksum[t];
    s[t] = own;
    __syncthreads();
    for (int off = 1; off < 1024; off <<= 1) {
        unsigned int v = (t >= off) ? s[t - off] : 0u;
        __syncthreads();
        s[t] += v;
        __syncthreads();
    }
    blockbase[t] = s[t] - own;   // exclusive
}

// ---- K2c: per-chunk exclusive scan + base -> global offsets ----
__global__ __launch_bounds__(256) void offsets_kernel(
    const unsigned int* __restrict__ counts, const unsigned int* __restrict__ blockbase,
    unsigned int* __restrict__ offsets, int n) {
    __shared__ unsigned int s[256];
    int t = threadIdx.x, b = blockIdx.x;
    unsigned int own = counts[b * 256 + t];
    s[t] = own;
    __syncthreads();
    for (int off = 1; off < 256; off <<= 1) {
        unsigned int v = (t >= off) ? s[t - off] : 0u;
        __syncthreads();
        s[t] += v;
        __syncthreads();
    }
    unsigned int incl = s[t] + blockbase[b];
    offsets[b * 256 + t] = incl - own;               // exclusive
    if (b == SCAN_BLOCKS - 1 && t == 255) offsets[NSEG] = incl;  // == n
}

// ---- K3: scatter point ids into cell-sorted order ----
__global__ __launch_bounds__(256) void reorder_kernel(
    const int* __restrict__ cell, const unsigned int* __restrict__ rank,
    const unsigned int* __restrict__ offsets, unsigned int* __restrict__ order, int n) {
    int p = blockIdx.x * blockDim.x + threadIdx.x;
    if (p >= n) return;
    int c = cell[p];
    order[offsets[c] + rank[p]] = (unsigned int)p;
}

// ---- K4: one wave per cell, lane = channel ----
// Point ids loaded once (coalesced) then broadcast via shuffle; up to 4
// independent x-row loads per group, all branches wave-uniform.
__global__ __launch_bounds__(256) void gather_kernel(
    const float* __restrict__ x, const unsigned int* __restrict__ offsets,
    const unsigned int* __restrict__ order, float* __restrict__ out) {
    int wave = (int)((blockIdx.x * blockDim.x + threadIdx.x) >> 6);
    int lane = threadIdx.x & 63;
    unsigned int s = offsets[wave];
    unsigned int e = offsets[wave + 1];

    size_t obase = (size_t)wave * NCH + lane;
    if (s == e) { out[obase] = 0.0f; return; }  // empty cell -> 0

    const float NEG_INF = -__builtin_inff();
    float acc = NEG_INF;

    for (unsigned int base = s; base < e; base += 64) {
        unsigned int rem = e - base;                 // wave-uniform
        unsigned int cnt = rem < 64u ? rem : 64u;
        // coalesced load of this chunk's point ids (clamped for tail lanes)
        unsigned int li = lane < cnt ? (unsigned int)lane : cnt - 1u;
        unsigned int myp = order[base + li];

        for (unsigned int j = 0; j < cnt; j += 4) {  // uniform trip count
            unsigned int m = cnt - j;
            unsigned int p0 = (unsigned int)__shfl((int)myp, (int)j, 64);
            float v0 = x[(size_t)p0 * NCH + lane];
            float v1 = NEG_INF, v2 = NEG_INF, v3 = NEG_INF;
            if (m > 1u) {
                unsigned int p1 = (unsigned int)__shfl((int)myp, (int)(j + 1), 64);
                v1 = x[(size_t)p1 * NCH + lane];
            }
            if (m > 2u) {
                unsigned int p2 = (unsigned int)__shfl((int)myp, (int)(j + 2), 64);
                v2 = x[(size_t)p2 * NCH + lane];
            }
            if (m > 3u) {
                unsigned int p3 = (unsigned int)__shfl((int)myp, (int)(j + 3), 64);
                v3 = x[(size_t)p3 * NCH + lane];
            }
            acc = fmaxf(acc, fmaxf(fmaxf(v0, v1), fmaxf(v2, v3)));
        }
    }
    out[obase] = acc;
}

extern "C" void kernel_launch(void* const* d_in, const int* in_sizes, int n_in,
                              void* d_out, int out_size, void* d_ws, size_t ws_size,
                              hipStream_t stream) {
    const float* x   = (const float*)d_in[0];
    const int* pos   = (const int*)d_in[1];
    const int* batch = (const int*)d_in[2];
    float* out = (float*)d_out;
    int n = in_sizes[2];

    // workspace layout (~14 MB)
    unsigned int* counts    = (unsigned int*)d_ws;          // NSEG
    unsigned int* offsets   = counts + NSEG;                // NSEG + 1
    unsigned int* blocksum  = offsets + NSEG + 1;           // 1024
    unsigned int* blockbase = blocksum + 1024;              // 1024
    unsigned int* rank      = blockbase + 1024;             // N
    int*          cell      = (int*)(rank + n);             // N
    unsigned int* order     = (unsigned int*)(cell + n);    // N

    hipMemsetAsync(counts, 0, (size_t)NSEG * sizeof(unsigned int), stream);

    int pblocks = (n + 255) / 256;
    count_kernel<<<pblocks, 256, 0, stream>>>(pos, batch, counts, rank, cell, n);
    reduce_kernel<<<SCAN_BLOCKS, 256, 0, stream>>>(counts, blocksum);
    scanblock_kernel<<<1, 1024, 0, stream>>>(blocksum, blockbase);
    offsets_kernel<<<SCAN_BLOCKS, 256, 0, stream>>>(counts, blockbase, offsets, n);
    reorder_kernel<<<pblocks, 256, 0, stream>>>(cell, rank, offsets, order, n);
    gather_kernel<<<NSEG / 4, 256, 0, stream>>>(x, offsets, order, out);
}